// Round 4
// baseline (948.951 us; speedup 1.0000x reference)
//
#include <hip/hip_runtime.h>

// PeerNet: out = relu-MLP with per-feature kNN-mean (k=6, 1D) in the middle.
// B=4096, D=1024, H1=128, H2=64, O=2. All fp32.
//
// ROUND 4 = MEASUREMENT ROUND. Real pipeline identical to Round 3
// (prep -> gemm1_mfma -> sort_window -> tail). Appended: 4 amplified
// profile replicas writing to scratch, each >43us so they surface in the
// rocprof top-5 with per-stage counters. Will be removed next round.
//   t_stage = prof_dur / REPS ; boundary B = (dur - 63.3 - sum_prof)/4.

#define NB   4096
#define DIN  1024
#define NH1  128
#define NH2  64

#define PROF_GEMM  16
#define PROF_SORTF 12
#define PROF_SORTH 16
#define PROF_TAIL  24

typedef _Float16 f16x8 __attribute__((ext_vector_type(8)));
typedef _Float16 f16x4 __attribute__((ext_vector_type(4)));
typedef float    f32x4 __attribute__((ext_vector_type(4)));

// opaque zero: defeats loop-invariant hoisting across rep loops
__device__ __forceinline__ unsigned opaque_zero() {
    unsigned zr = 0;
    asm volatile("" : "+v"(zr));
    return zr;
}

// ---------------------------------------------------------------------------
// prep: W1 [128][1024] fp32 -> Whi/Wlo f16 (hi = rn(w), lo = rn(w - hi)).
// ---------------------------------------------------------------------------
__global__ __launch_bounds__(256) void prep_w1(const float* __restrict__ W1,
                                               _Float16* __restrict__ Whi,
                                               _Float16* __restrict__ Wlo)
{
    const int i = (blockIdx.x * 256 + threadIdx.x) * 4;
    const float4 v = *(const float4*)&W1[i];
    const _Float16 h0 = (_Float16)v.x, h1 = (_Float16)v.y;
    const _Float16 h2 = (_Float16)v.z, h3 = (_Float16)v.w;
    f16x4 hv = {h0, h1, h2, h3};
    f16x4 lv = {(_Float16)(v.x - (float)h0), (_Float16)(v.y - (float)h1),
                (_Float16)(v.z - (float)h2), (_Float16)(v.w - (float)h3)};
    *(f16x4*)&Whi[i] = hv;
    *(f16x4*)&Wlo[i] = lv;
}

// ---------------------------------------------------------------------------
// GEMM1 via MFMA 16x16x32 f16, hi/lo split: h1T[n][m] = relu(x@W1^T + b1)^T.
// ---------------------------------------------------------------------------
__global__ __launch_bounds__(512) void gemm1_mfma(const float* __restrict__ x,
                                                  const _Float16* __restrict__ Whi,
                                                  const _Float16* __restrict__ Wlo,
                                                  const float* __restrict__ b1,
                                                  float* __restrict__ h1T)
{
    __shared__ _Float16 xhi[16 * 1032];
    __shared__ _Float16 xlo[16 * 1032];
    const int tid = threadIdx.x;
    const int m0  = blockIdx.x * 16;

    {
        const int r  = tid >> 5;
        const int kb = (tid & 31) * 4;
#pragma unroll
        for (int i = 0; i < 8; ++i) {
            const int k = kb + i * 128;
            const float4 v = *(const float4*)&x[(size_t)(m0 + r) * DIN + k];
            const _Float16 h0 = (_Float16)v.x, h1 = (_Float16)v.y;
            const _Float16 h2 = (_Float16)v.z, h3 = (_Float16)v.w;
            f16x4 hv = {h0, h1, h2, h3};
            f16x4 lv = {(_Float16)(v.x - (float)h0), (_Float16)(v.y - (float)h1),
                        (_Float16)(v.z - (float)h2), (_Float16)(v.w - (float)h3)};
            *(f16x4*)&xhi[r * 1032 + k] = hv;
            *(f16x4*)&xlo[r * 1032 + k] = lv;
        }
    }
    __syncthreads();

    const int lane = tid & 63;
    const int w    = tid >> 6;
    const int n0   = w * 16;
    const int fr   = lane & 15;
    const int fq   = lane >> 4;

    f32x4 acc = {0.f, 0.f, 0.f, 0.f};
    const _Float16* __restrict__ whp = &Whi[(size_t)(n0 + fr) * DIN + fq * 8];
    const _Float16* __restrict__ wlp = &Wlo[(size_t)(n0 + fr) * DIN + fq * 8];
    const _Float16* xh = &xhi[fr * 1032 + fq * 8];
    const _Float16* xl = &xlo[fr * 1032 + fq * 8];

#pragma unroll 4
    for (int ks = 0; ks < 32; ++ks) {
        const int k = ks * 32;
        const f16x8 ah = *(const f16x8*)&xh[k];
        const f16x8 al = *(const f16x8*)&xl[k];
        const f16x8 bh = *(const f16x8*)&whp[k];
        const f16x8 bl = *(const f16x8*)&wlp[k];
        acc = __builtin_amdgcn_mfma_f32_16x16x32_f16(ah, bh, acc, 0, 0, 0);
        acc = __builtin_amdgcn_mfma_f32_16x16x32_f16(ah, bl, acc, 0, 0, 0);
        acc = __builtin_amdgcn_mfma_f32_16x16x32_f16(al, bh, acc, 0, 0, 0);
    }

    const int n = n0 + fr;
    const float bv = b1[n];
    float4 o;
    o.x = fmaxf(acc[0] + bv, 0.f);
    o.y = fmaxf(acc[1] + bv, 0.f);
    o.z = fmaxf(acc[2] + bv, 0.f);
    o.w = fmaxf(acc[3] + bv, 0.f);
    *(float4*)&h1T[(size_t)n * NB + m0 + fq * 4] = o;
}

// ---------------------------------------------------------------------------
// Fused sort+window (R3): full-column bitonic in LDS, window on own half.
// ---------------------------------------------------------------------------
__global__ __launch_bounds__(1024) void sort_window_kernel(const float* __restrict__ h1T,
                                                           float* __restrict__ prtT)
{
    __shared__ float s[NB];
    const int t    = threadIdx.x;
    const int col  = blockIdx.x >> 1;
    const int half = blockIdx.x & 1;
    const float* __restrict__ src = h1T + (size_t)col * NB;

    float v[4];
#pragma unroll
    for (int q = 0; q < 4; ++q) v[q] = src[t + q * 1024];

#pragma unroll
    for (int k = 2; k <= 64; k <<= 1) {
#pragma unroll
        for (int j = k >> 1; j > 0; j >>= 1) {
#pragma unroll
            for (int q = 0; q < 4; ++q) {
                const int i = q * 1024 + t;
                const float p = __shfl_xor(v[q], j);
                const bool up  = ((i & k) == 0);
                const bool low = ((i & j) == 0);
                v[q] = (low == up) ? fminf(v[q], p) : fmaxf(v[q], p);
            }
        }
    }
#pragma unroll
    for (int q = 0; q < 4; ++q) s[t + q * 1024] = v[q];
    __syncthreads();

    for (int k = 128; k <= 4096; k <<= 1) {
        for (int j = k >> 1; j >= 64; j >>= 1) {
#pragma unroll
            for (int p = 0; p < 2; ++p) {
                const int c = t + p * 1024;
                const int i = ((c & ~(j - 1)) << 1) | (c & (j - 1));
                const int ixj = i | j;
                const float a = s[i], b = s[ixj];
                const bool up = ((i & k) == 0);
                if ((a > b) == up) { s[i] = b; s[ixj] = a; }
            }
            __syncthreads();
        }
#pragma unroll
        for (int q = 0; q < 4; ++q) v[q] = s[t + q * 1024];
#pragma unroll
        for (int j = 32; j > 0; j >>= 1) {
#pragma unroll
            for (int q = 0; q < 4; ++q) {
                const int i = q * 1024 + t;
                const float p = __shfl_xor(v[q], j);
                const bool up  = ((i & k) == 0);
                const bool low = ((i & j) == 0);
                v[q] = (low == up) ? fminf(v[q], p) : fmaxf(v[q], p);
            }
        }
#pragma unroll
        for (int q = 0; q < 4; ++q) s[t + q * 1024] = v[q];
        __syncthreads();
    }

#pragma unroll
    for (int p = 0; p < 2; ++p) {
        const int e   = half * 2048 + t + p * 1024;
        const float v0 = src[e];
        int lo = 0, hi = NB;
        while (lo < hi) {
            const int mid = (lo + hi) >> 1;
            if (s[mid] < v0) lo = mid + 1; else hi = mid;
        }
        int l = lo, h = lo;
        float sum = v0;
#pragma unroll
        for (int it = 0; it < 5; ++it) {
            const int li = (l > 0) ? l - 1 : 0;
            const int ri = (h < NB - 1) ? h + 1 : NB - 1;
            const float sl = s[li];
            const float sr = s[ri];
            const float dl = (l > 0) ? (v0 - sl) : 1e30f;
            const float dr = (h < NB - 1) ? (sr - v0) : 1e30f;
            if (dl <= dr) { sum += sl; l = li; }
            else          { sum += sr; h = ri; }
        }
        prtT[(size_t)col * NB + e] = sum * (1.0f / 6.0f);
    }
}

// ---------------------------------------------------------------------------
// Fused tail.
// ---------------------------------------------------------------------------
__global__ __launch_bounds__(256) void tail_kernel(const float* __restrict__ AT,
                                                   const float* __restrict__ Wpr,
                                                   const float* __restrict__ bpr,
                                                   const float* __restrict__ W2,
                                                   const float* __restrict__ b2,
                                                   const float* __restrict__ Wo,
                                                   const float* __restrict__ bo,
                                                   float* __restrict__ out)
{
    __shared__ float As[NH1 * 17];
    __shared__ float Bs[32 * 132];
    __shared__ float Ps[16 * 132];
    __shared__ float Rs[16 * 32];
    const int tid = threadIdx.x;
    const int m0  = blockIdx.x * 16;

    {
        const int row = tid >> 2;
        const int f   = (tid & 3) * 4;
#pragma unroll
        for (int h = 0; h < 2; ++h) {
            const int k = row + h * 64;
            const float4 v = *(const float4*)&AT[(size_t)k * NB + m0 + f];
            As[k * 17 + f + 0] = v.x;
            As[k * 17 + f + 1] = v.y;
            As[k * 17 + f + 2] = v.z;
            As[k * 17 + f + 3] = v.w;
        }
    }

    const int m  = tid & 15;
    const int g  = tid >> 4;
    const int n0 = g * 8;

    float acc[8];
#pragma unroll
    for (int j = 0; j < 8; ++j) acc[j] = 0.f;

    for (int k0 = 0; k0 < NH1; k0 += 32) {
        {
            const int n  = tid >> 1;
            const int ko = (tid & 1) * 16;
#pragma unroll
            for (int i4 = 0; i4 < 4; ++i4) {
                const float4 v = *(const float4*)&Wpr[(size_t)n * NH1 + k0 + ko + i4 * 4];
                Bs[(ko + i4 * 4 + 0) * 132 + n] = v.x;
                Bs[(ko + i4 * 4 + 1) * 132 + n] = v.y;
                Bs[(ko + i4 * 4 + 2) * 132 + n] = v.z;
                Bs[(ko + i4 * 4 + 3) * 132 + n] = v.w;
            }
        }
        __syncthreads();
#pragma unroll
        for (int kk = 0; kk < 32; ++kk) {
            const float a   = As[(k0 + kk) * 17 + m];
            const float4 b0 = *(const float4*)&Bs[kk * 132 + n0];
            const float4 b1 = *(const float4*)&Bs[kk * 132 + n0 + 4];
            acc[0] = fmaf(a, b0.x, acc[0]);
            acc[1] = fmaf(a, b0.y, acc[1]);
            acc[2] = fmaf(a, b0.z, acc[2]);
            acc[3] = fmaf(a, b0.w, acc[3]);
            acc[4] = fmaf(a, b1.x, acc[4]);
            acc[5] = fmaf(a, b1.y, acc[5]);
            acc[6] = fmaf(a, b1.z, acc[6]);
            acc[7] = fmaf(a, b1.w, acc[7]);
        }
        __syncthreads();
    }
#pragma unroll
    for (int j = 0; j < 8; ++j)
        Ps[m * 132 + n0 + j] = fmaxf(acc[j] + bpr[n0 + j], 0.f);
    __syncthreads();

    const int j0 = g * 4;
    float acc2[4] = {0.f, 0.f, 0.f, 0.f};
    for (int n0c = 0; n0c < NH1; n0c += 32) {
        {
            const int j2 = tid >> 2;
            const int no = (tid & 3) * 8;
#pragma unroll
            for (int i4 = 0; i4 < 2; ++i4) {
                const float4 v = *(const float4*)&W2[(size_t)j2 * NH1 + n0c + no + i4 * 4];
                Bs[(no + i4 * 4 + 0) * 68 + j2] = v.x;
                Bs[(no + i4 * 4 + 1) * 68 + j2] = v.y;
                Bs[(no + i4 * 4 + 2) * 68 + j2] = v.z;
                Bs[(no + i4 * 4 + 3) * 68 + j2] = v.w;
            }
        }
        __syncthreads();
#pragma unroll
        for (int nn = 0; nn < 32; ++nn) {
            const float p  = Ps[m * 132 + n0c + nn];
            const float4 w = *(const float4*)&Bs[nn * 68 + j0];
            acc2[0] = fmaf(p, w.x, acc2[0]);
            acc2[1] = fmaf(p, w.y, acc2[1]);
            acc2[2] = fmaf(p, w.z, acc2[2]);
            acc2[3] = fmaf(p, w.w, acc2[3]);
        }
        __syncthreads();
    }

    float po0 = 0.f, po1 = 0.f;
#pragma unroll
    for (int j = 0; j < 4; ++j) {
        const float h = fmaxf(acc2[j] + b2[j0 + j], 0.f);
        po0 = fmaf(h, Wo[j0 + j], po0);
        po1 = fmaf(h, Wo[NH2 + j0 + j], po1);
    }
    Rs[g * 32 + m * 2 + 0] = po0;
    Rs[g * 32 + m * 2 + 1] = po1;
    __syncthreads();
    if (tid < 32) {
        const int mm = tid >> 1, o = tid & 1;
        float sum = 0.f;
#pragma unroll
        for (int gg = 0; gg < 16; ++gg) sum += Rs[gg * 32 + mm * 2 + o];
        out[(size_t)(m0 + mm) * 2 + o] = sum + bo[o];
    }
}

// ===========================================================================
// PROFILE REPLICAS (measurement only; write scratch; removed next round)
// ===========================================================================

__global__ __launch_bounds__(512) void gemm1_profile(const float* __restrict__ x,
                                                     const _Float16* __restrict__ Whi,
                                                     const _Float16* __restrict__ Wlo,
                                                     const float* __restrict__ b1,
                                                     float* __restrict__ dst)
{
    __shared__ _Float16 xhi[16 * 1032];
    __shared__ _Float16 xlo[16 * 1032];
    const int tid = threadIdx.x;
    const int m0  = blockIdx.x * 16;

#pragma unroll 1
    for (int rep = 0; rep < PROF_GEMM; ++rep) {
        const unsigned zr = opaque_zero();
        const float* xp = x + zr;
        const _Float16* whb = Whi + zr;
        const _Float16* wlb = Wlo + zr;
        {
            const int r  = tid >> 5;
            const int kb = (tid & 31) * 4;
#pragma unroll
            for (int i = 0; i < 8; ++i) {
                const int k = kb + i * 128;
                const float4 v = *(const float4*)&xp[(size_t)(m0 + r) * DIN + k];
                const _Float16 h0 = (_Float16)v.x, h1 = (_Float16)v.y;
                const _Float16 h2 = (_Float16)v.z, h3 = (_Float16)v.w;
                f16x4 hv = {h0, h1, h2, h3};
                f16x4 lv = {(_Float16)(v.x - (float)h0), (_Float16)(v.y - (float)h1),
                            (_Float16)(v.z - (float)h2), (_Float16)(v.w - (float)h3)};
                *(f16x4*)&xhi[r * 1032 + k] = hv;
                *(f16x4*)&xlo[r * 1032 + k] = lv;
            }
        }
        __syncthreads();

        const int lane = tid & 63;
        const int w    = tid >> 6;
        const int n0   = w * 16;
        const int fr   = lane & 15;
        const int fq   = lane >> 4;

        f32x4 acc = {0.f, 0.f, 0.f, 0.f};
        const _Float16* whp = &whb[(size_t)(n0 + fr) * DIN + fq * 8];
        const _Float16* wlp = &wlb[(size_t)(n0 + fr) * DIN + fq * 8];
        const _Float16* xh = &xhi[fr * 1032 + fq * 8];
        const _Float16* xl = &xlo[fr * 1032 + fq * 8];

#pragma unroll 4
        for (int ks = 0; ks < 32; ++ks) {
            const int k = ks * 32;
            const f16x8 ah = *(const f16x8*)&xh[k];
            const f16x8 al = *(const f16x8*)&xl[k];
            const f16x8 bh = *(const f16x8*)&whp[k];
            const f16x8 bl = *(const f16x8*)&wlp[k];
            acc = __builtin_amdgcn_mfma_f32_16x16x32_f16(ah, bh, acc, 0, 0, 0);
            acc = __builtin_amdgcn_mfma_f32_16x16x32_f16(ah, bl, acc, 0, 0, 0);
            acc = __builtin_amdgcn_mfma_f32_16x16x32_f16(al, bh, acc, 0, 0, 0);
        }

        const int n = n0 + fr;
        const float bv = b1[n];
        float4 o;
        o.x = fmaxf(acc[0] + bv, 0.f);
        o.y = fmaxf(acc[1] + bv, 0.f);
        o.z = fmaxf(acc[2] + bv, 0.f);
        o.w = fmaxf(acc[3] + bv, 0.f);
        *(float4*)&dst[(size_t)n * NB + m0 + fq * 4] = o;
        __syncthreads();
    }
}

__global__ __launch_bounds__(1024) void sortfull_profile(const float* __restrict__ h1T,
                                                         float* __restrict__ dst)
{
    __shared__ float s[NB];
    const int t    = threadIdx.x;
    const int col  = blockIdx.x >> 1;
    const int half = blockIdx.x & 1;

#pragma unroll 1
    for (int rep = 0; rep < PROF_SORTF; ++rep) {
        const unsigned zr = opaque_zero();
        const float* src = h1T + (size_t)col * NB + zr;

        float v[4];
#pragma unroll
        for (int q = 0; q < 4; ++q) v[q] = src[t + q * 1024];

#pragma unroll
        for (int k = 2; k <= 64; k <<= 1) {
#pragma unroll
            for (int j = k >> 1; j > 0; j >>= 1) {
#pragma unroll
                for (int q = 0; q < 4; ++q) {
                    const int i = q * 1024 + t;
                    const float p = __shfl_xor(v[q], j);
                    const bool up  = ((i & k) == 0);
                    const bool low = ((i & j) == 0);
                    v[q] = (low == up) ? fminf(v[q], p) : fmaxf(v[q], p);
                }
            }
        }
#pragma unroll
        for (int q = 0; q < 4; ++q) s[t + q * 1024] = v[q];
        __syncthreads();

        for (int k = 128; k <= 4096; k <<= 1) {
            for (int j = k >> 1; j >= 64; j >>= 1) {
#pragma unroll
                for (int p = 0; p < 2; ++p) {
                    const int c = t + p * 1024;
                    const int i = ((c & ~(j - 1)) << 1) | (c & (j - 1));
                    const int ixj = i | j;
                    const float a = s[i], b = s[ixj];
                    const bool up = ((i & k) == 0);
                    if ((a > b) == up) { s[i] = b; s[ixj] = a; }
                }
                __syncthreads();
            }
#pragma unroll
            for (int q = 0; q < 4; ++q) v[q] = s[t + q * 1024];
#pragma unroll
            for (int j = 32; j > 0; j >>= 1) {
#pragma unroll
                for (int q = 0; q < 4; ++q) {
                    const int i = q * 1024 + t;
                    const float p = __shfl_xor(v[q], j);
                    const bool up  = ((i & k) == 0);
                    const bool low = ((i & j) == 0);
                    v[q] = (low == up) ? fminf(v[q], p) : fmaxf(v[q], p);
                }
            }
#pragma unroll
            for (int q = 0; q < 4; ++q) s[t + q * 1024] = v[q];
            __syncthreads();
        }

#pragma unroll
        for (int p = 0; p < 2; ++p) {
            const int e   = half * 2048 + t + p * 1024;
            const float v0 = src[e];
            int lo = 0, hi = NB;
            while (lo < hi) {
                const int mid = (lo + hi) >> 1;
                if (s[mid] < v0) lo = mid + 1; else hi = mid;
            }
            int l = lo, h = lo;
            float sum = v0;
#pragma unroll
            for (int it = 0; it < 5; ++it) {
                const int li = (l > 0) ? l - 1 : 0;
                const int ri = (h < NB - 1) ? h + 1 : NB - 1;
                const float sl = s[li];
                const float sr = s[ri];
                const float dl = (l > 0) ? (v0 - sl) : 1e30f;
                const float dr = (h < NB - 1) ? (sr - v0) : 1e30f;
                if (dl <= dr) { sum += sl; l = li; }
                else          { sum += sr; h = ri; }
            }
            dst[(size_t)col * NB + e] = sum * (1.0f / 6.0f);
        }
        __syncthreads();
    }
}

// R1-style half sort (512 thr, 2048 elems) for comparison
__global__ __launch_bounds__(512) void sorthalf_profile(const float* __restrict__ h1T,
                                                        float* __restrict__ dst)
{
    __shared__ float s[2048];
    const int t = threadIdx.x;
    const int col  = blockIdx.x >> 1;
    const int half = blockIdx.x & 1;

#pragma unroll 1
    for (int rep = 0; rep < PROF_SORTH; ++rep) {
        const unsigned zr = opaque_zero();
        const float* src = h1T + (size_t)col * NB + half * 2048 + zr;

        float v[4];
#pragma unroll
        for (int q = 0; q < 4; ++q) v[q] = src[t + q * 512];

#pragma unroll
        for (int k = 2; k <= 64; k <<= 1) {
#pragma unroll
            for (int j = k >> 1; j > 0; j >>= 1) {
#pragma unroll
                for (int q = 0; q < 4; ++q) {
                    const int i = q * 512 + t;
                    const float p = __shfl_xor(v[q], j);
                    const bool up  = ((i & k) == 0);
                    const bool low = ((i & j) == 0);
                    v[q] = (low == up) ? fminf(v[q], p) : fmaxf(v[q], p);
                }
            }
        }
#pragma unroll
        for (int q = 0; q < 4; ++q) s[t + q * 512] = v[q];
        __syncthreads();

        for (int k = 128; k <= 2048; k <<= 1) {
            for (int j = k >> 1; j >= 64; j >>= 1) {
#pragma unroll
                for (int p = 0; p < 2; ++p) {
                    const int c = t + p * 512;
                    const int i = ((c & ~(j - 1)) << 1) | (c & (j - 1));
                    const int ixj = i | j;
                    const float a = s[i], b = s[ixj];
                    const bool up = ((i & k) == 0);
                    if ((a > b) == up) { s[i] = b; s[ixj] = a; }
                }
                __syncthreads();
            }
#pragma unroll
            for (int q = 0; q < 4; ++q) v[q] = s[t + q * 512];
#pragma unroll
            for (int j = 32; j > 0; j >>= 1) {
#pragma unroll
                for (int q = 0; q < 4; ++q) {
                    const int i = q * 512 + t;
                    const float p = __shfl_xor(v[q], j);
                    const bool up  = ((i & k) == 0);
                    const bool low = ((i & j) == 0);
                    v[q] = (low == up) ? fminf(v[q], p) : fmaxf(v[q], p);
                }
            }
#pragma unroll
            for (int q = 0; q < 4; ++q) s[t + q * 512] = v[q];
            __syncthreads();
        }

        float* dstp = dst + (size_t)col * NB + half * 2048;
#pragma unroll
        for (int q = 0; q < 4; ++q) dstp[t + q * 512] = s[t + q * 512];
        __syncthreads();
    }
}

__global__ __launch_bounds__(256) void tail_profile(const float* __restrict__ AT,
                                                    const float* __restrict__ Wpr,
                                                    const float* __restrict__ bpr,
                                                    const float* __restrict__ W2,
                                                    const float* __restrict__ b2,
                                                    const float* __restrict__ Wo,
                                                    const float* __restrict__ bo,
                                                    float* __restrict__ out)
{
    __shared__ float As[NH1 * 17];
    __shared__ float Bs[32 * 132];
    __shared__ float Ps[16 * 132];
    __shared__ float Rs[16 * 32];
    const int tid = threadIdx.x;
    const int m0  = blockIdx.x * 16;

#pragma unroll 1
    for (int rep = 0; rep < PROF_TAIL; ++rep) {
        const unsigned zr = opaque_zero();
        const float* ATp = AT + zr;
        {
            const int row = tid >> 2;
            const int f   = (tid & 3) * 4;
#pragma unroll
            for (int h = 0; h < 2; ++h) {
                const int k = row + h * 64;
                const float4 v = *(const float4*)&ATp[(size_t)k * NB + m0 + f];
                As[k * 17 + f + 0] = v.x;
                As[k * 17 + f + 1] = v.y;
                As[k * 17 + f + 2] = v.z;
                As[k * 17 + f + 3] = v.w;
            }
        }

        const int m  = tid & 15;
        const int g  = tid >> 4;
        const int n0 = g * 8;

        float acc[8];
#pragma unroll
        for (int j = 0; j < 8; ++j) acc[j] = 0.f;

        for (int k0 = 0; k0 < NH1; k0 += 32) {
            {
                const int n  = tid >> 1;
                const int ko = (tid & 1) * 16;
#pragma unroll
                for (int i4 = 0; i4 < 4; ++i4) {
                    const float4 v = *(const float4*)&Wpr[(size_t)n * NH1 + k0 + ko + i4 * 4];
                    Bs[(ko + i4 * 4 + 0) * 132 + n] = v.x;
                    Bs[(ko + i4 * 4 + 1) * 132 + n] = v.y;
                    Bs[(ko + i4 * 4 + 2) * 132 + n] = v.z;
                    Bs[(ko + i4 * 4 + 3) * 132 + n] = v.w;
                }
            }
            __syncthreads();
#pragma unroll
            for (int kk = 0; kk < 32; ++kk) {
                const float a   = As[(k0 + kk) * 17 + m];
                const float4 b0 = *(const float4*)&Bs[kk * 132 + n0];
                const float4 b1 = *(const float4*)&Bs[kk * 132 + n0 + 4];
                acc[0] = fmaf(a, b0.x, acc[0]);
                acc[1] = fmaf(a, b0.y, acc[1]);
                acc[2] = fmaf(a, b0.z, acc[2]);
                acc[3] = fmaf(a, b0.w, acc[3]);
                acc[4] = fmaf(a, b1.x, acc[4]);
                acc[5] = fmaf(a, b1.y, acc[5]);
                acc[6] = fmaf(a, b1.z, acc[6]);
                acc[7] = fmaf(a, b1.w, acc[7]);
            }
            __syncthreads();
        }
#pragma unroll
        for (int j = 0; j < 8; ++j)
            Ps[m * 132 + n0 + j] = fmaxf(acc[j] + bpr[n0 + j], 0.f);
        __syncthreads();

        const int j0 = g * 4;
        float acc2[4] = {0.f, 0.f, 0.f, 0.f};
        for (int n0c = 0; n0c < NH1; n0c += 32) {
            {
                const int j2 = tid >> 2;
                const int no = (tid & 3) * 8;
#pragma unroll
                for (int i4 = 0; i4 < 2; ++i4) {
                    const float4 v = *(const float4*)&W2[(size_t)j2 * NH1 + n0c + no + i4 * 4];
                    Bs[(no + i4 * 4 + 0) * 68 + j2] = v.x;
                    Bs[(no + i4 * 4 + 1) * 68 + j2] = v.y;
                    Bs[(no + i4 * 4 + 2) * 68 + j2] = v.z;
                    Bs[(no + i4 * 4 + 3) * 68 + j2] = v.w;
                }
            }
            __syncthreads();
#pragma unroll
            for (int nn = 0; nn < 32; ++nn) {
                const float p  = Ps[m * 132 + n0c + nn];
                const float4 w = *(const float4*)&Bs[nn * 68 + j0];
                acc2[0] = fmaf(p, w.x, acc2[0]);
                acc2[1] = fmaf(p, w.y, acc2[1]);
                acc2[2] = fmaf(p, w.z, acc2[2]);
                acc2[3] = fmaf(p, w.w, acc2[3]);
            }
            __syncthreads();
        }

        float po0 = 0.f, po1 = 0.f;
#pragma unroll
        for (int j = 0; j < 4; ++j) {
            const float h = fmaxf(acc2[j] + b2[j0 + j], 0.f);
            po0 = fmaf(h, Wo[j0 + j], po0);
            po1 = fmaf(h, Wo[NH2 + j0 + j], po1);
        }
        Rs[g * 32 + m * 2 + 0] = po0;
        Rs[g * 32 + m * 2 + 1] = po1;
        __syncthreads();
        if (tid < 32) {
            const int mm = tid >> 1, o = tid & 1;
            float sum = 0.f;
#pragma unroll
            for (int gg = 0; gg < 16; ++gg) sum += Rs[gg * 32 + mm * 2 + o];
            out[(size_t)(m0 + mm) * 2 + o] = sum + bo[o];
        }
        __syncthreads();
    }
}

extern "C" void kernel_launch(void* const* d_in, const int* in_sizes, int n_in,
                              void* d_out, int out_size, void* d_ws, size_t ws_size,
                              hipStream_t stream)
{
    const float* x   = (const float*)d_in[0];
    const float* W1  = (const float*)d_in[1];
    const float* b1  = (const float*)d_in[2];
    const float* Wpr = (const float*)d_in[3];
    const float* bpr = (const float*)d_in[4];
    const float* W2  = (const float*)d_in[5];
    const float* b2  = (const float*)d_in[6];
    const float* Wo  = (const float*)d_in[7];
    const float* bo  = (const float*)d_in[8];

    float* ws     = (float*)d_ws;
    float* h1T    = ws;                               // [128][4096]  2 MB
    float* prtT   = h1T + NH1 * NB;                   // [128][4096]  2 MB
    _Float16* Whi = (_Float16*)(prtT + NH1 * NB);     // [128][1024]  256 KB
    _Float16* Wlo = Whi + NH1 * DIN;                  // [128][1024]  256 KB
    float* scrA   = (float*)(Wlo + NH1 * DIN);        // scratch 2 MB
    float* scrB   = scrA + NH1 * NB;                  // scratch 2 MB
    float* scrC   = scrB + NH1 * NB;                  // scratch 2 MB
    float* scrOut = scrC + NH1 * NB;                  // scratch 32 KB

    // ---- real pipeline (identical to Round 3) ----
    prep_w1<<<dim3(NH1 * DIN / 4 / 256), 256, 0, stream>>>(W1, Whi, Wlo);
    gemm1_mfma<<<dim3(NB / 16), 512, 0, stream>>>(x, Whi, Wlo, b1, h1T);
    sort_window_kernel<<<dim3(NH1 * 2), 1024, 0, stream>>>(h1T, prtT);
    tail_kernel<<<dim3(NB / 16), 256, 0, stream>>>(prtT, Wpr, bpr, W2, b2, Wo, bo,
                                                   (float*)d_out);

    // ---- profile replicas (scratch outputs; measurement only) ----
    gemm1_profile<<<dim3(NB / 16), 512, 0, stream>>>(x, Whi, Wlo, b1, scrA);
    sortfull_profile<<<dim3(NH1 * 2), 1024, 0, stream>>>(h1T, scrB);
    sorthalf_profile<<<dim3(NH1 * 2), 512, 0, stream>>>(h1T, scrC);
    tail_profile<<<dim3(NB / 16), 256, 0, stream>>>(prtT, Wpr, bpr, W2, b2, Wo, bo,
                                                    scrOut);
}

// Round 5
// 77.651 us; speedup vs baseline: 12.2207x; 12.2207x over previous
//
#include <hip/hip_runtime.h>

// PeerNet: out = relu-MLP with per-feature kNN-mean (k=6, 1D) in the middle.
// B=4096, D=1024, H1=128, H2=64, O=2. All fp32.
//
// Pipeline: prep (W1->f16 hi/lo), gemm1 (MFMA f16 hi/lo), sort_chunk
// (4x 1024-elem bitonic per column, 2 blocks/CU), window (6-nearest
// two-pointer directly on 4 sorted chunks, no merge build), tail (whole-
// weight LDS staging, 4 barriers).
// Lessons: R2 grid.sync ~30us each -> never fuse dependent grid stages.
// R4 profiling: full-column sort was 23.5us = 37% of pipeline.

#define NB   4096
#define DIN  1024
#define NH1  128
#define NH2  64

typedef _Float16 f16x8 __attribute__((ext_vector_type(8)));
typedef _Float16 f16x4 __attribute__((ext_vector_type(4)));
typedef float    f32x4 __attribute__((ext_vector_type(4)));

// ---------------------------------------------------------------------------
// prep: W1 [128][1024] fp32 -> Whi/Wlo f16 (hi = rn(w), lo = rn(w - hi)).
// ---------------------------------------------------------------------------
__global__ __launch_bounds__(256) void prep_w1(const float* __restrict__ W1,
                                               _Float16* __restrict__ Whi,
                                               _Float16* __restrict__ Wlo)
{
    const int i = (blockIdx.x * 256 + threadIdx.x) * 4;
    const float4 v = *(const float4*)&W1[i];
    const _Float16 h0 = (_Float16)v.x, h1 = (_Float16)v.y;
    const _Float16 h2 = (_Float16)v.z, h3 = (_Float16)v.w;
    f16x4 hv = {h0, h1, h2, h3};
    f16x4 lv = {(_Float16)(v.x - (float)h0), (_Float16)(v.y - (float)h1),
                (_Float16)(v.z - (float)h2), (_Float16)(v.w - (float)h3)};
    *(f16x4*)&Whi[i] = hv;
    *(f16x4*)&Wlo[i] = lv;
}

// ---------------------------------------------------------------------------
// GEMM1 via MFMA 16x16x32 f16, hi/lo split: h1T[n][m] = relu(x@W1^T + b1)^T.
// Grid 256 blocks x 512 threads (8 waves). Block: 16 batch rows, all 128 n.
// ---------------------------------------------------------------------------
__global__ __launch_bounds__(512) void gemm1_mfma(const float* __restrict__ x,
                                                  const _Float16* __restrict__ Whi,
                                                  const _Float16* __restrict__ Wlo,
                                                  const float* __restrict__ b1,
                                                  float* __restrict__ h1T)
{
    __shared__ _Float16 xhi[16 * 1032];
    __shared__ _Float16 xlo[16 * 1032];
    const int tid = threadIdx.x;
    const int m0  = blockIdx.x * 16;

    {   // stage + convert: thread t -> row t>>5, cols (t&31)*4 + i*128
        const int r  = tid >> 5;
        const int kb = (tid & 31) * 4;
#pragma unroll
        for (int i = 0; i < 8; ++i) {
            const int k = kb + i * 128;
            const float4 v = *(const float4*)&x[(size_t)(m0 + r) * DIN + k];
            const _Float16 h0 = (_Float16)v.x, h1 = (_Float16)v.y;
            const _Float16 h2 = (_Float16)v.z, h3 = (_Float16)v.w;
            f16x4 hv = {h0, h1, h2, h3};
            f16x4 lv = {(_Float16)(v.x - (float)h0), (_Float16)(v.y - (float)h1),
                        (_Float16)(v.z - (float)h2), (_Float16)(v.w - (float)h3)};
            *(f16x4*)&xhi[r * 1032 + k] = hv;
            *(f16x4*)&xlo[r * 1032 + k] = lv;
        }
    }
    __syncthreads();

    const int lane = tid & 63;
    const int w    = tid >> 6;          // 0..7 -> n-tile
    const int n0   = w * 16;
    const int fr   = lane & 15;
    const int fq   = lane >> 4;         // 0..3

    f32x4 acc = {0.f, 0.f, 0.f, 0.f};
    const _Float16* __restrict__ whp = &Whi[(size_t)(n0 + fr) * DIN + fq * 8];
    const _Float16* __restrict__ wlp = &Wlo[(size_t)(n0 + fr) * DIN + fq * 8];
    const _Float16* xh = &xhi[fr * 1032 + fq * 8];
    const _Float16* xl = &xlo[fr * 1032 + fq * 8];

#pragma unroll 4
    for (int ks = 0; ks < 32; ++ks) {
        const int k = ks * 32;
        const f16x8 ah = *(const f16x8*)&xh[k];
        const f16x8 al = *(const f16x8*)&xl[k];
        const f16x8 bh = *(const f16x8*)&whp[k];
        const f16x8 bl = *(const f16x8*)&wlp[k];
        acc = __builtin_amdgcn_mfma_f32_16x16x32_f16(ah, bh, acc, 0, 0, 0);
        acc = __builtin_amdgcn_mfma_f32_16x16x32_f16(ah, bl, acc, 0, 0, 0);
        acc = __builtin_amdgcn_mfma_f32_16x16x32_f16(al, bh, acc, 0, 0, 0);
    }

    const int n = n0 + fr;
    const float bv = b1[n];
    float4 o;
    o.x = fmaxf(acc[0] + bv, 0.f);
    o.y = fmaxf(acc[1] + bv, 0.f);
    o.z = fmaxf(acc[2] + bv, 0.f);
    o.w = fmaxf(acc[3] + bv, 0.f);
    *(float4*)&h1T[(size_t)n * NB + m0 + fq * 4] = o;
}

// ---------------------------------------------------------------------------
// sort_chunk: grid 512 = 128 cols x 4 chunks, 256 threads. Bitonic-sort a
// 1024-element chunk (hybrid: j<=32 via __shfl_xor in regs, j>=64 via LDS).
// 2 blocks/CU -> barrier latency overlaps. Thread t holds i = t + q*256.
// ---------------------------------------------------------------------------
__global__ __launch_bounds__(256) void sort_chunk_kernel(const float* __restrict__ h1T,
                                                         float* __restrict__ sorted)
{
    __shared__ float s[1024];
    const int t     = threadIdx.x;
    const int col   = blockIdx.x >> 2;
    const int chunk = blockIdx.x & 3;
    const float* __restrict__ src = h1T + (size_t)col * NB + chunk * 1024;

    float v[4];
#pragma unroll
    for (int q = 0; q < 4; ++q) v[q] = src[t + q * 256];

    // k = 2..64 entirely in registers (0 barriers)
#pragma unroll
    for (int k = 2; k <= 64; k <<= 1) {
#pragma unroll
        for (int j = k >> 1; j > 0; j >>= 1) {
#pragma unroll
            for (int q = 0; q < 4; ++q) {
                const int i = q * 256 + t;
                const float p = __shfl_xor(v[q], j);
                const bool up  = ((i & k) == 0);
                const bool low = ((i & j) == 0);
                v[q] = (low == up) ? fminf(v[q], p) : fmaxf(v[q], p);
            }
        }
    }
#pragma unroll
    for (int q = 0; q < 4; ++q) s[t + q * 256] = v[q];
    __syncthreads();

    for (int k = 128; k <= 1024; k <<= 1) {
        for (int j = k >> 1; j >= 64; j >>= 1) {
#pragma unroll
            for (int p = 0; p < 2; ++p) {
                const int c = t + p * 256;
                const int i = ((c & ~(j - 1)) << 1) | (c & (j - 1));
                const int ixj = i | j;
                const float a = s[i], b = s[ixj];
                const float mn = fminf(a, b), mx = fmaxf(a, b);
                const bool up = ((i & k) == 0);
                s[i]   = up ? mn : mx;
                s[ixj] = up ? mx : mn;
            }
            __syncthreads();
        }
        // j = 32..1 in registers
#pragma unroll
        for (int q = 0; q < 4; ++q) v[q] = s[t + q * 256];
#pragma unroll
        for (int j = 32; j > 0; j >>= 1) {
#pragma unroll
            for (int q = 0; q < 4; ++q) {
                const int i = q * 256 + t;
                const float p = __shfl_xor(v[q], j);
                const bool up  = ((i & k) == 0);
                const bool low = ((i & j) == 0);
                v[q] = (low == up) ? fminf(v[q], p) : fmaxf(v[q], p);
            }
        }
#pragma unroll
        for (int q = 0; q < 4; ++q) s[t + q * 256] = v[q];
        __syncthreads();
    }

    float* __restrict__ dst = sorted + (size_t)col * NB + chunk * 1024;
#pragma unroll
    for (int q = 0; q < 4; ++q) dst[t + q * 256] = s[t + q * 256];
}

// ---------------------------------------------------------------------------
// window: grid 512 = 128 cols x 4 segs, 256 threads, 4 elems/thread.
// Loads the column's 4 sorted chunks into LDS; per element: 4 binary
// searches + greedy 5-step expansion over 8 candidates (two-pointer on 4
// sorted lists == two-pointer on their merge). Self-copy skipped by bumping
// the right pointer of the element's own chunk. Ties: prefer left (<=),
// matching the previous passing kernels.
// ---------------------------------------------------------------------------
__global__ __launch_bounds__(256) void window_kernel(const float* __restrict__ h1T,
                                                     const float* __restrict__ sorted,
                                                     float* __restrict__ prtT)
{
    __shared__ float s[NB];
    const int t   = threadIdx.x;
    const int col = blockIdx.x >> 2;
    const int seg = blockIdx.x & 3;
    const float* __restrict__ srt = sorted + (size_t)col * NB;
#pragma unroll
    for (int p = 0; p < 4; ++p) {
        const int i4 = (p * 256 + t) * 4;
        *(float4*)&s[i4] = *(const float4*)&srt[i4];
    }
    __syncthreads();

    const float* __restrict__ S0 = s;
    const float* __restrict__ S1 = s + 1024;
    const float* __restrict__ S2 = s + 2048;
    const float* __restrict__ S3 = s + 3072;
    const float* __restrict__ colp = h1T + (size_t)col * NB;

#pragma unroll
    for (int q = 0; q < 4; ++q) {
        const int e   = seg * 1024 + q * 256 + t;
        const float v = colp[e];

        int l0, l1, l2, l3;
        { int lo = 0, hi = 1024; while (lo < hi) { const int mid = (lo + hi) >> 1; if (S0[mid] < v) lo = mid + 1; else hi = mid; } l0 = lo; }
        { int lo = 0, hi = 1024; while (lo < hi) { const int mid = (lo + hi) >> 1; if (S1[mid] < v) lo = mid + 1; else hi = mid; } l1 = lo; }
        { int lo = 0, hi = 1024; while (lo < hi) { const int mid = (lo + hi) >> 1; if (S2[mid] < v) lo = mid + 1; else hi = mid; } l2 = lo; }
        { int lo = 0, hi = 1024; while (lo < hi) { const int mid = (lo + hi) >> 1; if (S3[mid] < v) lo = mid + 1; else hi = mid; } l3 = lo; }

        int r0 = l0, r1 = l1, r2 = l2, r3 = l3;
        const int cs = e >> 10;     // self chunk: skip one copy of v
        if      (cs == 0) ++r0;
        else if (cs == 1) ++r1;
        else if (cs == 2) ++r2;
        else              ++r3;

        float sum = v;  // self
#pragma unroll
        for (int it = 0; it < 5; ++it) {
            const float dl0 = (l0 > 0) ? v - S0[l0 - 1] : 1e30f;
            const float dl1 = (l1 > 0) ? v - S1[l1 - 1] : 1e30f;
            const float dl2 = (l2 > 0) ? v - S2[l2 - 1] : 1e30f;
            const float dl3 = (l3 > 0) ? v - S3[l3 - 1] : 1e30f;
            const float dr0 = (r0 < 1024) ? S0[r0] - v : 1e30f;
            const float dr1 = (r1 < 1024) ? S1[r1] - v : 1e30f;
            const float dr2 = (r2 < 1024) ? S2[r2] - v : 1e30f;
            const float dr3 = (r3 < 1024) ? S3[r3] - v : 1e30f;
            const float bl = fminf(fminf(dl0, dl1), fminf(dl2, dl3));
            const float br = fminf(fminf(dr0, dr1), fminf(dr2, dr3));
            if (bl <= br) {
                if      (dl0 <= bl) sum += S0[--l0];
                else if (dl1 <= bl) sum += S1[--l1];
                else if (dl2 <= bl) sum += S2[--l2];
                else                sum += S3[--l3];
            } else {
                if      (dr0 <= br) sum += S0[r0++];
                else if (dr1 <= br) sum += S1[r1++];
                else if (dr2 <= br) sum += S2[r2++];
                else                sum += S3[r3++];
            }
        }
        prtT[(size_t)col * NB + e] = sum * (1.0f / 6.0f);
    }
}

// ---------------------------------------------------------------------------
// Fused tail: out = (relu(relu(prT^T @ Wpr^T + bpr) @ W2^T + b2)) @ Wo^T + bo
// v2: whole Wpr (67.6 KB) and W2 staged in one shot each -> 4 barriers total
// (was ~18). LDS ~87 KB, grid 256 x 256 (1 block/CU).
// ---------------------------------------------------------------------------
__global__ __launch_bounds__(256) void tail_kernel(const float* __restrict__ AT,
                                                   const float* __restrict__ Wpr,
                                                   const float* __restrict__ bpr,
                                                   const float* __restrict__ W2,
                                                   const float* __restrict__ b2,
                                                   const float* __restrict__ Wo,
                                                   const float* __restrict__ bo,
                                                   float* __restrict__ out)
{
    __shared__ float As[NH1 * 17];    // A^T tile [k=128][m=16]
    __shared__ float Bs[NH1 * 132];   // Wpr full [k][n]; reused for W2 [nn][68]
    __shared__ float Ps[16 * 132];    // pr tile [m][n=128]
    __shared__ float Rs[16 * 32];     // out reduction [g][m*2+o]
    const int tid = threadIdx.x;
    const int m0  = blockIdx.x * 16;

    {   // load A tile: As[k][m] = AT[k*NB + m0 + m]
        const int row = tid >> 2;
        const int f   = (tid & 3) * 4;
#pragma unroll
        for (int h = 0; h < 2; ++h) {
            const int k = row + h * 64;
            const float4 v = *(const float4*)&AT[(size_t)k * NB + m0 + f];
            As[k * 17 + f + 0] = v.x;
            As[k * 17 + f + 1] = v.y;
            As[k * 17 + f + 2] = v.z;
            As[k * 17 + f + 3] = v.w;
        }
    }
    {   // stage FULL Wpr: Bs[k][n] = Wpr[n][k]; n = tid>>1, k-half = tid&1
        const int n  = tid >> 1;
        const int kb = (tid & 1) * 64;
#pragma unroll
        for (int i4 = 0; i4 < 16; ++i4) {
            const float4 v = *(const float4*)&Wpr[(size_t)n * NH1 + kb + i4 * 4];
            Bs[(kb + i4 * 4 + 0) * 132 + n] = v.x;
            Bs[(kb + i4 * 4 + 1) * 132 + n] = v.y;
            Bs[(kb + i4 * 4 + 2) * 132 + n] = v.z;
            Bs[(kb + i4 * 4 + 3) * 132 + n] = v.w;
        }
    }
    __syncthreads();

    const int m  = tid & 15;
    const int g  = tid >> 4;     // 0..15
    const int n0 = g * 8;

    float acc[8];
#pragma unroll
    for (int j = 0; j < 8; ++j) acc[j] = 0.f;

#pragma unroll 8
    for (int kk = 0; kk < NH1; ++kk) {
        const float a   = As[kk * 17 + m];
        const float4 b0 = *(const float4*)&Bs[kk * 132 + n0];
        const float4 b1 = *(const float4*)&Bs[kk * 132 + n0 + 4];
        acc[0] = fmaf(a, b0.x, acc[0]);
        acc[1] = fmaf(a, b0.y, acc[1]);
        acc[2] = fmaf(a, b0.z, acc[2]);
        acc[3] = fmaf(a, b0.w, acc[3]);
        acc[4] = fmaf(a, b1.x, acc[4]);
        acc[5] = fmaf(a, b1.y, acc[5]);
        acc[6] = fmaf(a, b1.z, acc[6]);
        acc[7] = fmaf(a, b1.w, acc[7]);
    }
#pragma unroll
    for (int j = 0; j < 8; ++j)
        Ps[m * 132 + n0 + j] = fmaxf(acc[j] + bpr[n0 + j], 0.f);
    __syncthreads();

    {   // stage FULL W2 (reuse Bs): Bs[nn][j2] = W2[j2][nn], stride 68
        const int j2 = tid >> 2;
        const int nb = (tid & 3) * 32;
#pragma unroll
        for (int i4 = 0; i4 < 8; ++i4) {
            const float4 v = *(const float4*)&W2[(size_t)j2 * NH1 + nb + i4 * 4];
            Bs[(nb + i4 * 4 + 0) * 68 + j2] = v.x;
            Bs[(nb + i4 * 4 + 1) * 68 + j2] = v.y;
            Bs[(nb + i4 * 4 + 2) * 68 + j2] = v.z;
            Bs[(nb + i4 * 4 + 3) * 68 + j2] = v.w;
        }
    }
    __syncthreads();

    const int j0 = g * 4;
    float acc2[4] = {0.f, 0.f, 0.f, 0.f};
#pragma unroll 8
    for (int nn = 0; nn < NH1; ++nn) {
        const float p  = Ps[m * 132 + nn];
        const float4 w = *(const float4*)&Bs[nn * 68 + j0];
        acc2[0] = fmaf(p, w.x, acc2[0]);
        acc2[1] = fmaf(p, w.y, acc2[1]);
        acc2[2] = fmaf(p, w.z, acc2[2]);
        acc2[3] = fmaf(p, w.w, acc2[3]);
    }

    float po0 = 0.f, po1 = 0.f;
#pragma unroll
    for (int j = 0; j < 4; ++j) {
        const float h = fmaxf(acc2[j] + b2[j0 + j], 0.f);
        po0 = fmaf(h, Wo[j0 + j], po0);
        po1 = fmaf(h, Wo[NH2 + j0 + j], po1);
    }
    Rs[g * 32 + m * 2 + 0] = po0;
    Rs[g * 32 + m * 2 + 1] = po1;
    __syncthreads();
    if (tid < 32) {
        const int mm = tid >> 1, o = tid & 1;
        float sum = 0.f;
#pragma unroll
        for (int gg = 0; gg < 16; ++gg) sum += Rs[gg * 32 + mm * 2 + o];
        out[(size_t)(m0 + mm) * 2 + o] = sum + bo[o];
    }
}

extern "C" void kernel_launch(void* const* d_in, const int* in_sizes, int n_in,
                              void* d_out, int out_size, void* d_ws, size_t ws_size,
                              hipStream_t stream)
{
    const float* x   = (const float*)d_in[0];
    const float* W1  = (const float*)d_in[1];
    const float* b1  = (const float*)d_in[2];
    const float* Wpr = (const float*)d_in[3];
    const float* bpr = (const float*)d_in[4];
    const float* W2  = (const float*)d_in[5];
    const float* b2  = (const float*)d_in[6];
    const float* Wo  = (const float*)d_in[7];
    const float* bo  = (const float*)d_in[8];

    float* ws     = (float*)d_ws;
    float* h1T    = ws;                               // [128][4096]  2 MB
    float* sorted = h1T + NH1 * NB;                   // [128][4096]  2 MB
    float* prtT   = sorted + NH1 * NB;                // [128][4096]  2 MB
    _Float16* Whi = (_Float16*)(prtT + NH1 * NB);     // [128][1024]  256 KB
    _Float16* Wlo = Whi + NH1 * DIN;                  // [128][1024]  256 KB

    prep_w1<<<dim3(NH1 * DIN / 4 / 256), 256, 0, stream>>>(W1, Whi, Wlo);
    gemm1_mfma<<<dim3(NB / 16), 512, 0, stream>>>(x, Whi, Wlo, b1, h1T);
    sort_chunk_kernel<<<dim3(NH1 * 4), 256, 0, stream>>>(h1T, sorted);
    window_kernel<<<dim3(NH1 * 4), 256, 0, stream>>>(h1T, sorted, prtT);
    tail_kernel<<<dim3(NB / 16), 256, 0, stream>>>(prtT, Wpr, bpr, W2, b2, Wo, bo,
                                                   (float*)d_out);
}

// Round 6
// 62.351 us; speedup vs baseline: 15.2195x; 1.2454x over previous
//
#include <hip/hip_runtime.h>

// PeerNet: out = relu-MLP with per-feature kNN-mean (k=6, 1D) in the middle.
// B=4096, D=1024, H1=128, H2=64, O=2. All fp32.
//
// Pipeline: prep (W1->f16 hi/lo), gemm1 (MFMA f16 hi/lo), sort_chunk
// (4x 1024-elem ascending bitonic per column, grid 512 = 2 blocks/CU),
// merge_window (bitonic MERGE k=2048,4096 of the 4 chunks in LDS --
// chunks 1,3 loaded reversed to form asc/desc/asc/desc -- then R3's
// single-search 6-NN window), tail (whole-weight LDS staging, 4 barriers).
//
// Lessons: R2 grid.sync ~30us each -> never fuse dependent grid stages.
// R4 profiling: full-column fused sort_window = 23.5us (37% of pipeline).
// R5: 4-list search window = 45us latency disaster at 2 blocks/CU; but
// chunk-sort ~8us and tail_v2 ~8us proven good.

#define NB   4096
#define DIN  1024
#define NH1  128
#define NH2  64

typedef _Float16 f16x8 __attribute__((ext_vector_type(8)));
typedef _Float16 f16x4 __attribute__((ext_vector_type(4)));
typedef float    f32x4 __attribute__((ext_vector_type(4)));

// ---------------------------------------------------------------------------
// prep: W1 [128][1024] fp32 -> Whi/Wlo f16 (hi = rn(w), lo = rn(w - hi)).
// ---------------------------------------------------------------------------
__global__ __launch_bounds__(256) void prep_w1(const float* __restrict__ W1,
                                               _Float16* __restrict__ Whi,
                                               _Float16* __restrict__ Wlo)
{
    const int i = (blockIdx.x * 256 + threadIdx.x) * 4;
    const float4 v = *(const float4*)&W1[i];
    const _Float16 h0 = (_Float16)v.x, h1 = (_Float16)v.y;
    const _Float16 h2 = (_Float16)v.z, h3 = (_Float16)v.w;
    f16x4 hv = {h0, h1, h2, h3};
    f16x4 lv = {(_Float16)(v.x - (float)h0), (_Float16)(v.y - (float)h1),
                (_Float16)(v.z - (float)h2), (_Float16)(v.w - (float)h3)};
    *(f16x4*)&Whi[i] = hv;
    *(f16x4*)&Wlo[i] = lv;
}

// ---------------------------------------------------------------------------
// GEMM1 via MFMA 16x16x32 f16, hi/lo split: h1T[n][m] = relu(x@W1^T + b1)^T.
// Grid 256 blocks x 512 threads (8 waves). Block: 16 batch rows, all 128 n.
// ---------------------------------------------------------------------------
__global__ __launch_bounds__(512) void gemm1_mfma(const float* __restrict__ x,
                                                  const _Float16* __restrict__ Whi,
                                                  const _Float16* __restrict__ Wlo,
                                                  const float* __restrict__ b1,
                                                  float* __restrict__ h1T)
{
    __shared__ _Float16 xhi[16 * 1032];
    __shared__ _Float16 xlo[16 * 1032];
    const int tid = threadIdx.x;
    const int m0  = blockIdx.x * 16;

    {   // stage + convert: thread t -> row t>>5, cols (t&31)*4 + i*128
        const int r  = tid >> 5;
        const int kb = (tid & 31) * 4;
#pragma unroll
        for (int i = 0; i < 8; ++i) {
            const int k = kb + i * 128;
            const float4 v = *(const float4*)&x[(size_t)(m0 + r) * DIN + k];
            const _Float16 h0 = (_Float16)v.x, h1 = (_Float16)v.y;
            const _Float16 h2 = (_Float16)v.z, h3 = (_Float16)v.w;
            f16x4 hv = {h0, h1, h2, h3};
            f16x4 lv = {(_Float16)(v.x - (float)h0), (_Float16)(v.y - (float)h1),
                        (_Float16)(v.z - (float)h2), (_Float16)(v.w - (float)h3)};
            *(f16x4*)&xhi[r * 1032 + k] = hv;
            *(f16x4*)&xlo[r * 1032 + k] = lv;
        }
    }
    __syncthreads();

    const int lane = tid & 63;
    const int w    = tid >> 6;          // 0..7 -> n-tile
    const int n0   = w * 16;
    const int fr   = lane & 15;
    const int fq   = lane >> 4;         // 0..3

    f32x4 acc = {0.f, 0.f, 0.f, 0.f};
    const _Float16* __restrict__ whp = &Whi[(size_t)(n0 + fr) * DIN + fq * 8];
    const _Float16* __restrict__ wlp = &Wlo[(size_t)(n0 + fr) * DIN + fq * 8];
    const _Float16* xh = &xhi[fr * 1032 + fq * 8];
    const _Float16* xl = &xlo[fr * 1032 + fq * 8];

#pragma unroll 4
    for (int ks = 0; ks < 32; ++ks) {
        const int k = ks * 32;
        const f16x8 ah = *(const f16x8*)&xh[k];
        const f16x8 al = *(const f16x8*)&xl[k];
        const f16x8 bh = *(const f16x8*)&whp[k];
        const f16x8 bl = *(const f16x8*)&wlp[k];
        acc = __builtin_amdgcn_mfma_f32_16x16x32_f16(ah, bh, acc, 0, 0, 0);
        acc = __builtin_amdgcn_mfma_f32_16x16x32_f16(ah, bl, acc, 0, 0, 0);
        acc = __builtin_amdgcn_mfma_f32_16x16x32_f16(al, bh, acc, 0, 0, 0);
    }

    const int n = n0 + fr;
    const float bv = b1[n];
    float4 o;
    o.x = fmaxf(acc[0] + bv, 0.f);
    o.y = fmaxf(acc[1] + bv, 0.f);
    o.z = fmaxf(acc[2] + bv, 0.f);
    o.w = fmaxf(acc[3] + bv, 0.f);
    *(float4*)&h1T[(size_t)n * NB + m0 + fq * 4] = o;
}

// ---------------------------------------------------------------------------
// sort_chunk: grid 512 = 128 cols x 4 chunks, 256 threads. Ascending bitonic
// sort of a 1024-element chunk (hybrid: j<=32 via __shfl_xor in regs,
// j>=64 via LDS). 2 blocks/CU. Thread t holds i = t + q*256.
// ---------------------------------------------------------------------------
__global__ __launch_bounds__(256) void sort_chunk_kernel(const float* __restrict__ h1T,
                                                         float* __restrict__ sorted)
{
    __shared__ float s[1024];
    const int t     = threadIdx.x;
    const int col   = blockIdx.x >> 2;
    const int chunk = blockIdx.x & 3;
    const float* __restrict__ src = h1T + (size_t)col * NB + chunk * 1024;

    float v[4];
#pragma unroll
    for (int q = 0; q < 4; ++q) v[q] = src[t + q * 256];

    // k = 2..64 entirely in registers (0 barriers)
#pragma unroll
    for (int k = 2; k <= 64; k <<= 1) {
#pragma unroll
        for (int j = k >> 1; j > 0; j >>= 1) {
#pragma unroll
            for (int q = 0; q < 4; ++q) {
                const int i = q * 256 + t;
                const float p = __shfl_xor(v[q], j);
                const bool up  = ((i & k) == 0);
                const bool low = ((i & j) == 0);
                v[q] = (low == up) ? fminf(v[q], p) : fmaxf(v[q], p);
            }
        }
    }
#pragma unroll
    for (int q = 0; q < 4; ++q) s[t + q * 256] = v[q];
    __syncthreads();

    for (int k = 128; k <= 1024; k <<= 1) {
        for (int j = k >> 1; j >= 64; j >>= 1) {
#pragma unroll
            for (int p = 0; p < 2; ++p) {
                const int c = t + p * 256;
                const int i = ((c & ~(j - 1)) << 1) | (c & (j - 1));
                const int ixj = i | j;
                const float a = s[i], b = s[ixj];
                const float mn = fminf(a, b), mx = fmaxf(a, b);
                const bool up = ((i & k) == 0);
                s[i]   = up ? mn : mx;
                s[ixj] = up ? mx : mn;
            }
            __syncthreads();
        }
        // j = 32..1 in registers
#pragma unroll
        for (int q = 0; q < 4; ++q) v[q] = s[t + q * 256];
#pragma unroll
        for (int j = 32; j > 0; j >>= 1) {
#pragma unroll
            for (int q = 0; q < 4; ++q) {
                const int i = q * 256 + t;
                const float p = __shfl_xor(v[q], j);
                const bool up  = ((i & k) == 0);
                const bool low = ((i & j) == 0);
                v[q] = (low == up) ? fminf(v[q], p) : fmaxf(v[q], p);
            }
        }
#pragma unroll
        for (int q = 0; q < 4; ++q) s[t + q * 256] = v[q];
        __syncthreads();
    }

    float* __restrict__ dst = sorted + (size_t)col * NB + chunk * 1024;
#pragma unroll
    for (int q = 0; q < 4; ++q) dst[t + q * 256] = s[t + q * 256];
}

// ---------------------------------------------------------------------------
// merge_window: grid 256 = 128 cols x 2 halves, 1024 threads.
// Loads the 4 ascending chunks with chunks 1,3 index-reversed (asc/desc/
// asc/desc), runs bitonic MERGE stages k=2048 (j=1024..1) and k=4096
// (j=2048..1) -- 11 LDS passes + 2x6 shfl passes, ~30% of a full sort --
// yielding the fully-sorted column in LDS. Then R3's proven window: per
// original element, 1 binary search + greedy 5-step 2-candidate expansion
// (prefer-left ties). Each block windows its own half (2 elems/thread).
// ---------------------------------------------------------------------------
__global__ __launch_bounds__(1024) void merge_window_kernel(const float* __restrict__ h1T,
                                                            const float* __restrict__ sorted,
                                                            float* __restrict__ prtT)
{
    __shared__ float s[NB];
    const int t    = threadIdx.x;
    const int col  = blockIdx.x >> 1;
    const int half = blockIdx.x & 1;
    const float* __restrict__ srt = sorted + (size_t)col * NB;

    // load; reverse chunks 1 and 3 -> asc,desc,asc,desc (bitonic input)
#pragma unroll
    for (int q = 0; q < 4; ++q) {
        const int p     = t + q * 1024;
        const int chunk = p >> 10;
        const int off   = p & 1023;
        const int so    = (chunk & 1) ? ((chunk << 10) | (1023 - off)) : p;
        s[p] = srt[so];
    }
    __syncthreads();

    float v[4];
    for (int k = 2048; k <= 4096; k <<= 1) {
        for (int j = k >> 1; j >= 64; j >>= 1) {
#pragma unroll
            for (int pp = 0; pp < 2; ++pp) {
                const int c = t + pp * 1024;
                const int i = ((c & ~(j - 1)) << 1) | (c & (j - 1));
                const int ixj = i | j;
                const float a = s[i], b = s[ixj];
                const float mn = fminf(a, b), mx = fmaxf(a, b);
                const bool up = ((i & k) == 0);
                s[i]   = up ? mn : mx;
                s[ixj] = up ? mx : mn;
            }
            __syncthreads();
        }
        // j = 32..1 in registers
#pragma unroll
        for (int q = 0; q < 4; ++q) v[q] = s[t + q * 1024];
#pragma unroll
        for (int j = 32; j > 0; j >>= 1) {
#pragma unroll
            for (int q = 0; q < 4; ++q) {
                const int i = q * 1024 + t;
                const float p = __shfl_xor(v[q], j);
                const bool up  = ((i & k) == 0);
                const bool low = ((i & j) == 0);
                v[q] = (low == up) ? fminf(v[q], p) : fmaxf(v[q], p);
            }
        }
#pragma unroll
        for (int q = 0; q < 4; ++q) s[t + q * 1024] = v[q];
        __syncthreads();
    }

    // ---- 6-nearest window phase on this block's half --------------------
    const float* __restrict__ colp = h1T + (size_t)col * NB;
#pragma unroll
    for (int p = 0; p < 2; ++p) {
        const int e    = half * 2048 + t + p * 1024;
        const float v0 = colp[e];
        int lo = 0, hi = NB;
        while (lo < hi) {
            const int mid = (lo + hi) >> 1;
            if (s[mid] < v0) lo = mid + 1; else hi = mid;
        }
        int l = lo, h = lo;
        float sum = v0;  // self
#pragma unroll
        for (int it = 0; it < 5; ++it) {
            const int li = (l > 0) ? l - 1 : 0;
            const int ri = (h < NB - 1) ? h + 1 : NB - 1;
            const float sl = s[li];
            const float sr = s[ri];
            const float dl = (l > 0) ? (v0 - sl) : 1e30f;
            const float dr = (h < NB - 1) ? (sr - v0) : 1e30f;
            if (dl <= dr) { sum += sl; l = li; }
            else          { sum += sr; h = ri; }
        }
        prtT[(size_t)col * NB + e] = sum * (1.0f / 6.0f);
    }
}

// ---------------------------------------------------------------------------
// Fused tail: out = (relu(relu(prT^T @ Wpr^T + bpr) @ W2^T + b2)) @ Wo^T + bo
// Whole Wpr and W2 staged in one shot each -> 4 barriers total. LDS ~87 KB.
// ---------------------------------------------------------------------------
__global__ __launch_bounds__(256) void tail_kernel(const float* __restrict__ AT,
                                                   const float* __restrict__ Wpr,
                                                   const float* __restrict__ bpr,
                                                   const float* __restrict__ W2,
                                                   const float* __restrict__ b2,
                                                   const float* __restrict__ Wo,
                                                   const float* __restrict__ bo,
                                                   float* __restrict__ out)
{
    __shared__ float As[NH1 * 17];    // A^T tile [k=128][m=16]
    __shared__ float Bs[NH1 * 132];   // Wpr full [k][n]; reused for W2 [nn][68]
    __shared__ float Ps[16 * 132];    // pr tile [m][n=128]
    __shared__ float Rs[16 * 32];     // out reduction [g][m*2+o]
    const int tid = threadIdx.x;
    const int m0  = blockIdx.x * 16;

    {   // load A tile: As[k][m] = AT[k*NB + m0 + m]
        const int row = tid >> 2;
        const int f   = (tid & 3) * 4;
#pragma unroll
        for (int h = 0; h < 2; ++h) {
            const int k = row + h * 64;
            const float4 v = *(const float4*)&AT[(size_t)k * NB + m0 + f];
            As[k * 17 + f + 0] = v.x;
            As[k * 17 + f + 1] = v.y;
            As[k * 17 + f + 2] = v.z;
            As[k * 17 + f + 3] = v.w;
        }
    }
    {   // stage FULL Wpr: Bs[k][n] = Wpr[n][k]; n = tid>>1, k-half = tid&1
        const int n  = tid >> 1;
        const int kb = (tid & 1) * 64;
#pragma unroll
        for (int i4 = 0; i4 < 16; ++i4) {
            const float4 v = *(const float4*)&Wpr[(size_t)n * NH1 + kb + i4 * 4];
            Bs[(kb + i4 * 4 + 0) * 132 + n] = v.x;
            Bs[(kb + i4 * 4 + 1) * 132 + n] = v.y;
            Bs[(kb + i4 * 4 + 2) * 132 + n] = v.z;
            Bs[(kb + i4 * 4 + 3) * 132 + n] = v.w;
        }
    }
    __syncthreads();

    const int m  = tid & 15;
    const int g  = tid >> 4;     // 0..15
    const int n0 = g * 8;

    float acc[8];
#pragma unroll
    for (int j = 0; j < 8; ++j) acc[j] = 0.f;

#pragma unroll 8
    for (int kk = 0; kk < NH1; ++kk) {
        const float a   = As[kk * 17 + m];
        const float4 b0 = *(const float4*)&Bs[kk * 132 + n0];
        const float4 b1 = *(const float4*)&Bs[kk * 132 + n0 + 4];
        acc[0] = fmaf(a, b0.x, acc[0]);
        acc[1] = fmaf(a, b0.y, acc[1]);
        acc[2] = fmaf(a, b0.z, acc[2]);
        acc[3] = fmaf(a, b0.w, acc[3]);
        acc[4] = fmaf(a, b1.x, acc[4]);
        acc[5] = fmaf(a, b1.y, acc[5]);
        acc[6] = fmaf(a, b1.z, acc[6]);
        acc[7] = fmaf(a, b1.w, acc[7]);
    }
#pragma unroll
    for (int j = 0; j < 8; ++j)
        Ps[m * 132 + n0 + j] = fmaxf(acc[j] + bpr[n0 + j], 0.f);
    __syncthreads();

    {   // stage FULL W2 (reuse Bs): Bs[nn][j2] = W2[j2][nn], stride 68
        const int j2 = tid >> 2;
        const int nb = (tid & 3) * 32;
#pragma unroll
        for (int i4 = 0; i4 < 8; ++i4) {
            const float4 v = *(const float4*)&W2[(size_t)j2 * NH1 + nb + i4 * 4];
            Bs[(nb + i4 * 4 + 0) * 68 + j2] = v.x;
            Bs[(nb + i4 * 4 + 1) * 68 + j2] = v.y;
            Bs[(nb + i4 * 4 + 2) * 68 + j2] = v.z;
            Bs[(nb + i4 * 4 + 3) * 68 + j2] = v.w;
        }
    }
    __syncthreads();

    const int j0 = g * 4;
    float acc2[4] = {0.f, 0.f, 0.f, 0.f};
#pragma unroll 8
    for (int nn = 0; nn < NH1; ++nn) {
        const float p  = Ps[m * 132 + nn];
        const float4 w = *(const float4*)&Bs[nn * 68 + j0];
        acc2[0] = fmaf(p, w.x, acc2[0]);
        acc2[1] = fmaf(p, w.y, acc2[1]);
        acc2[2] = fmaf(p, w.z, acc2[2]);
        acc2[3] = fmaf(p, w.w, acc2[3]);
    }

    float po0 = 0.f, po1 = 0.f;
#pragma unroll
    for (int j = 0; j < 4; ++j) {
        const float h = fmaxf(acc2[j] + b2[j0 + j], 0.f);
        po0 = fmaf(h, Wo[j0 + j], po0);
        po1 = fmaf(h, Wo[NH2 + j0 + j], po1);
    }
    Rs[g * 32 + m * 2 + 0] = po0;
    Rs[g * 32 + m * 2 + 1] = po1;
    __syncthreads();
    if (tid < 32) {
        const int mm = tid >> 1, o = tid & 1;
        float sum = 0.f;
#pragma unroll
        for (int gg = 0; gg < 16; ++gg) sum += Rs[gg * 32 + mm * 2 + o];
        out[(size_t)(m0 + mm) * 2 + o] = sum + bo[o];
    }
}

extern "C" void kernel_launch(void* const* d_in, const int* in_sizes, int n_in,
                              void* d_out, int out_size, void* d_ws, size_t ws_size,
                              hipStream_t stream)
{
    const float* x   = (const float*)d_in[0];
    const float* W1  = (const float*)d_in[1];
    const float* b1  = (const float*)d_in[2];
    const float* Wpr = (const float*)d_in[3];
    const float* bpr = (const float*)d_in[4];
    const float* W2  = (const float*)d_in[5];
    const float* b2  = (const float*)d_in[6];
    const float* Wo  = (const float*)d_in[7];
    const float* bo  = (const float*)d_in[8];

    float* ws     = (float*)d_ws;
    float* h1T    = ws;                               // [128][4096]  2 MB
    float* sorted = h1T + NH1 * NB;                   // [128][4096]  2 MB
    float* prtT   = sorted + NH1 * NB;                // [128][4096]  2 MB
    _Float16* Whi = (_Float16*)(prtT + NH1 * NB);     // [128][1024]  256 KB
    _Float16* Wlo = Whi + NH1 * DIN;                  // [128][1024]  256 KB

    prep_w1<<<dim3(NH1 * DIN / 4 / 256), 256, 0, stream>>>(W1, Whi, Wlo);
    gemm1_mfma<<<dim3(NB / 16), 512, 0, stream>>>(x, Whi, Wlo, b1, h1T);
    sort_chunk_kernel<<<dim3(NH1 * 4), 256, 0, stream>>>(h1T, sorted);
    merge_window_kernel<<<dim3(NH1 * 2), 1024, 0, stream>>>(h1T, sorted, prtT);
    tail_kernel<<<dim3(NB / 16), 256, 0, stream>>>(prtT, Wpr, bpr, W2, b2, Wo, bo,
                                                   (float*)d_out);
}